// Round 14
// baseline (93.575 us; speedup 1.0000x reference)
//
#include <hip/hip_runtime.h>
#include <math.h>

#define RG 61
#define CG 61
#define NP 3721           // RG*CG
#define NSEG 3722         // NP+1
#define NCLS 10
#define THRESHV 0.7f
#define BIGI 0x3FFFFFFF

#define CHS 51            // ODD chunk stride: img banks 19c mod 32 -> <=2-way
#define ROWF (64*CHS)     // 3264 floats per staged row
#define PROW 640          // part row stride (610 used)
#define NBLK 1024         // 64 wr x 16 rg

// constant-address-space view of W: uniform scalar loads -> s_load into SGPRs
typedef __attribute__((address_space(4))) const float cfl;

// ---------------------------------------------------------------------------
// Kernel 1: partial logits, W-reuse-amortized.
// Block = (wr, rg): ONE window row wr (W slice 1920 f = 7.7KB -> fits 16KB
// scalar L1, shared by all 4 waves) and 4 OUTPUT rows r = 4rg..4rg+3.
// Wave wv owns K-quarter wv: W base = W + wr*1920 + wv*480 (AS4 -> s_load).
// Thread = column c, acc[4][10] (4 output rows). Per j-step (one K-pair):
//   5 s_load_dwordx4 (imm offsets) + 4 ds_read_b64 (ONE base VGPR, offsets
//   t*13056+8j all fold to imm) + 160 cy of v_fmac.
// -> 4x the per-W-fetch compute window of every previous round; latency
// amortized even at 3 waves/SIMD, on scalar OR vector path.
// img: 4 rows (r-clamped) staged chunked [t][ch][CHS=51]; 52.2KB -> 3 blk/CU.
// Cross-wave K-sum in LDS (simg reused); store 610 floats/output-row.
// ---------------------------------------------------------------------------
__global__ __launch_bounds__(256, 3) void wod_logits_part(
    const float* __restrict__ img,   // (1024,1024,3)
    const float* __restrict__ W,     // (12288,10)
    float* __restrict__ part)        // (61*64, PROW)
{
    __shared__ float simg[4 * ROWF]; // 52224 B
    const int tid = threadIdx.x;
    // bijective XCD swizzle: 1024 = 8*128
    const int o  = ((blockIdx.x & 7) << 7) + (blockIdx.x >> 3);
    const int wr = o >> 4;           // window row [0,64)
    const int rg = o & 15;           // output-row quad [0,16)

    // ---- stage 4 image rows (r = 4rg+t clamped to 60), chunked [ch][CHS] ----
    for (int u = tid; u < 3072; u += 256) {
        const int t  = u / 768;
        const int v  = u - t * 768;
        const int p0 = v * 4;
        int rr = 4 * rg + t; if (rr > 60) rr = 60;
        const float4 x4 = *(const float4*)(img + (size_t)(16 * rr + wr) * 3072 + p0);
        const int ch = p0 / 48;             // p0%48 in {0,..,44}: never crosses
        float* d = simg + t * ROWF + ch * CHS + (p0 - ch * 48);
        d[0] = x4.x; d[1] = x4.y; d[2] = x4.z; d[3] = x4.w;
    }
    __syncthreads();

    const int wv = __builtin_amdgcn_readfirstlane(tid >> 6);  // K-quarter [0,4)
    const int c  = tid & 63;
    const int cx = c > 60 ? 60 : c;         // dup lanes clamped

    const cfl*   wq = (const cfl*)W + wr * 1920 + wv * 480;   // uniform
    const float* x0 = simg + (cx + wv) * CHS;   // ch = cx+wv <= 63; ONE base

    float acc[4][NCLS];
    #pragma unroll
    for (int t = 0; t < 4; ++t)
        #pragma unroll
        for (int k = 0; k < NCLS; ++k) acc[t][k] = 0.f;

    #pragma unroll
    for (int j = 0; j < 24; ++j) {          // K-pair within quarter
        float w_[20];
        #pragma unroll
        for (int k = 0; k < 20; ++k) w_[k] = wq[j * 20 + k];  // s_load x16+x4
        #pragma unroll
        for (int t = 0; t < 4; ++t) {
            const float2 x = *(const float2*)(x0 + t * ROWF + 2 * j); // imm off
            #pragma unroll
            for (int k = 0; k < NCLS; ++k) {
                acc[t][k] = fmaf(x.x, w_[k],      acc[t][k]);
                acc[t][k] = fmaf(x.y, w_[k + 10], acc[t][k]);
            }
        }
    }

    // ---- cross-wave K-sum in LDS (reuse simg), store 610/output-row ----
    __syncthreads();                 // all img reads done
    float* scratch = simg;           // [wv][t][640]
    {
        float* sc = scratch + wv * 2560 + c * 10;
        #pragma unroll
        for (int t = 0; t < 4; ++t)
            #pragma unroll
            for (int k = 0; k < NCLS; ++k)
                sc[t * 640 + k] = acc[t][k];
    }
    __syncthreads();
    for (int u = tid; u < 2560; u += 256) {
        const int t = u / 640, e = u - t * 640;
        const int rr = 4 * rg + t;
        if (rr <= 60 && e < 610) {
            const int b = t * 640 + e;
            part[(size_t)(rr * 64 + wr) * PROW + e] =
                scratch[b] + scratch[2560 + b] + scratch[5120 + b] + scratch[7680 + b];
        }
    }
}

// ---------------------------------------------------------------------------
// Kernel 2: sum 64 wr-slices per output row + bias + softmax + prob + mask.
// One block per r.
// ---------------------------------------------------------------------------
__global__ __launch_bounds__(256) void wod_reduce(
    const float* __restrict__ part,   // (61*64, PROW)
    const float* __restrict__ bias,   // (10)
    float* __restrict__ out_prob,     // (61,61,10)
    int* __restrict__ mask)           // (10,3721)
{
    __shared__ float lg[610];
    const int r   = blockIdx.x;
    const int tid = threadIdx.x;
    const float* pb = part + (size_t)r * 64 * PROW;

    for (int t = tid; t < 610; t += 256) {
        float s = bias[t - (t / 10) * 10];
        #pragma unroll 8
        for (int wr = 0; wr < 64; ++wr) s += pb[wr * PROW + t];
        lg[t] = s;
    }
    __syncthreads();

    for (int c = tid; c < CG; c += 256) {
        float l[NCLS];
        #pragma unroll
        for (int k = 0; k < NCLS; ++k) l[k] = lg[c * 10 + k];
        float m = -1e30f;
        #pragma unroll
        for (int k = 0; k < NCLS; ++k) m = fmaxf(m, l[k]);
        float ex[NCLS], sm = 0.f;
        #pragma unroll
        for (int k = 0; k < NCLS; ++k) { ex[k] = expf(l[k] - m); sm += ex[k]; }
        const float inv = 1.f / sm;
        const int cell = r * CG + c;
        #pragma unroll
        for (int k = 0; k < NCLS; ++k) {
            const float pr = ex[k] * inv;
            out_prob[cell * 10 + k] = pr;
            mask[k * NP + cell] = (pr > THRESHV) ? 1 : 0;
        }
    }
}

// ---------------------------------------------------------------------------
// Kernel 3: connected components (min-label propagation in LDS) + labels +
// boxes + valid, all fused. One block per class. (Unchanged, proven.)
// ---------------------------------------------------------------------------
__global__ __launch_bounds__(256) void wod_cc(
    const int* __restrict__ mask,     // (10,3721)
    float* __restrict__ out_lbl,      // (61,61,10) as float
    float* __restrict__ out_box,      // (10,3722,4)
    float* __restrict__ out_valid)    // (10,3722)
{
    const int k = blockIdx.x;
    const int tid = threadIdx.x;
    __shared__ int lbl[NP];
    __shared__ int ext0[NSEG], ext1[NSEG];
    __shared__ int changed;

    const int* mk = mask + k * NP;
    for (int idx = tid; idx < NP; idx += 256)
        lbl[idx] = mk[idx] ? (idx + 1) : 0;
    if (tid == 0) changed = 0;
    __syncthreads();

    for (;;) {
        for (int idx = tid; idx < NP; idx += 256) {
            int v = lbl[idx];
            if (v) {
                const int rr = idx / CG;
                const int cc = idx - rr * CG;
                int best = v;
                if (rr > 0)      { int n = lbl[idx - CG]; if (n && n < best) best = n; }
                if (rr < RG - 1) { int n = lbl[idx + CG]; if (n && n < best) best = n; }
                if (cc > 0)      { int n = lbl[idx - 1];  if (n && n < best) best = n; }
                if (cc < CG - 1) { int n = lbl[idx + 1];  if (n && n < best) best = n; }
                if (best < v) { lbl[idx] = best; changed = 1; }
            }
        }
        __syncthreads();
        const bool stop = (changed == 0);
        __syncthreads();           // all reads of `changed` done before reset
        if (stop) break;
        if (tid == 0) changed = 0;
        __syncthreads();
    }

    // labels out (transposed to (r,c,k))
    for (int idx = tid; idx < NP; idx += 256)
        out_lbl[idx * NCLS + k] = (float)lbl[idx];

    float* boxk = out_box + k * NSEG * 4;
    float* valk = out_valid + k * NSEG;

    // pass 1: rmin / cmin
    for (int s2 = tid; s2 < NSEG; s2 += 256) { ext0[s2] = BIGI; ext1[s2] = BIGI; }
    __syncthreads();
    for (int idx = tid; idx < NP; idx += 256) {
        const int v = lbl[idx];
        if (v) {
            const int rr = idx / CG, cc = idx - rr * CG;
            atomicMin(&ext0[v], rr);
            atomicMin(&ext1[v], cc);
        }
    }
    __syncthreads();
    for (int s2 = tid; s2 < NSEG; s2 += 256) {
        const bool valid = (s2 > 0) && (ext0[s2] != BIGI);
        boxk[s2 * 4 + 0] = valid ? (float)(ext0[s2] - 1) : -1.f;
        boxk[s2 * 4 + 1] = valid ? (float)(ext1[s2] - 1) : -1.f;
        valk[s2] = valid ? 1.f : 0.f;
    }
    __syncthreads();

    // pass 2: rmax / cmax
    for (int s2 = tid; s2 < NSEG; s2 += 256) { ext0[s2] = -1; ext1[s2] = -1; }
    __syncthreads();
    for (int idx = tid; idx < NP; idx += 256) {
        const int v = lbl[idx];
        if (v) {
            const int rr = idx / CG, cc = idx - rr * CG;
            atomicMax(&ext0[v], rr);
            atomicMax(&ext1[v], cc);
        }
    }
    __syncthreads();
    for (int s2 = tid; s2 < NSEG; s2 += 256) {
        const bool valid = (s2 > 0) && (ext0[s2] >= 0);
        boxk[s2 * 4 + 2] = valid ? (float)(ext0[s2] + 1) : -1.f;
        boxk[s2 * 4 + 3] = valid ? (float)(ext1[s2] + 1) : -1.f;
    }
}

// ---------------------------------------------------------------------------
extern "C" void kernel_launch(void* const* d_in, const int* in_sizes, int n_in,
                              void* d_out, int out_size, void* d_ws, size_t ws_size,
                              hipStream_t stream) {
    (void)in_sizes; (void)n_in; (void)out_size; (void)ws_size;
    const float* img = (const float*)d_in[0];
    const float* W   = (const float*)d_in[1];
    const float* b   = (const float*)d_in[2];

    float* out       = (float*)d_out;
    float* out_prob  = out;                       // 37210
    float* out_lbl   = out + 37210;               // 37210
    float* out_box   = out + 74420;               // 148880
    float* out_valid = out + 223300;              // 37220

    int*   mask = (int*)d_ws;                        // 10*3721 ints
    float* part = (float*)((int*)d_ws + NCLS * NP);  // 61*64*640 floats ~10MB

    hipLaunchKernelGGL(wod_logits_part, dim3(NBLK), dim3(256), 0, stream,
                       img, W, part);
    hipLaunchKernelGGL(wod_reduce, dim3(RG), dim3(256), 0, stream,
                       part, b, out_prob, mask);
    hipLaunchKernelGGL(wod_cc, dim3(NCLS), dim3(256), 0, stream,
                       mask, out_lbl, out_box, out_valid);
}

// Round 15
// 91.817 us; speedup vs baseline: 1.0191x; 1.0191x over previous
//
#include <hip/hip_runtime.h>
#include <math.h>

#define RG 61
#define CG 61
#define NP 3721           // RG*CG
#define NSEG 3722         // NP+1
#define NCLS 10
#define THRESHV 0.7f
#define BIGI 0x3FFFFFFF

#define CHS 49            // ODD chunk stride: banks 17(c+wv) mod 32 -> 2-way free
#define ROWF (64*CHS)     // 3136 floats per staged row
#define PROW 640          // part row stride (610 used)
#define NBLK 1024         // 64 wr x 16 rg

// ---------------------------------------------------------------------------
// Kernel 1: partial logits — ALL main-loop operands from LDS.
// Block = (wr, rg): one window row wr, 4 output rows r=4rg..4rg+3.
// Stage ONCE per block: img rows (4 x 3136 f, chunked [ch][CHS=49]) and the
// W row-slice (1920 f). Inner loop (wave wv = K-quarter, lane = column c):
//   5 ds_read_b128 W, SAME ADDRESS across the wave -> broadcast, conflict-free
//   4 ds_read_b64 img (banks 17(c+wv) bijective mod 32 -> 2-way = free)
//   80 v_fmac (160 cy/wave)
// Zero global/SMEM ops in the loop -> no L2/sL1 latency to hide (round-14
// failure mode eliminated); DS latency is short and compiler-pipelined.
// LDS 57856B -> 2 blocks/CU (8 waves). Cross-wave K-sum in LDS (simg reuse).
// ---------------------------------------------------------------------------
__global__ __launch_bounds__(256, 2) void wod_logits_part(
    const float* __restrict__ img,   // (1024,1024,3)
    const float* __restrict__ W,     // (12288,10)
    float* __restrict__ part)        // (61*64, PROW)
{
    __shared__ float simg[4 * ROWF]; // 50176 B
    __shared__ float sw[1920];       // 7680 B
    const int tid = threadIdx.x;
    // bijective XCD swizzle: 1024 = 8*128
    const int o  = ((blockIdx.x & 7) << 7) + (blockIdx.x >> 3);
    const int wr = o >> 4;           // window row [0,64)
    const int rg = o & 15;           // output-row quad [0,16)

    // ---- stage W row-slice: 1920 contiguous floats ----
    const float* wsrc = W + wr * 1920;
    for (int v = tid; v < 480; v += 256)
        *(float4*)(sw + v * 4) = *(const float4*)(wsrc + v * 4);

    // ---- stage 4 image rows (r = 4rg+t clamped to 60), chunked [ch][CHS] ----
    for (int u = tid; u < 3072; u += 256) {
        const int t  = u / 768;
        const int v  = u - t * 768;
        const int p0 = v * 4;
        int rr = 4 * rg + t; if (rr > 60) rr = 60;
        const float4 x4 = *(const float4*)(img + (size_t)(16 * rr + wr) * 3072 + p0);
        const int ch = p0 / 48;             // p0%48 in {0,..,44}: never crosses
        float* d = simg + t * ROWF + ch * CHS + (p0 - ch * 48);
        d[0] = x4.x; d[1] = x4.y; d[2] = x4.z; d[3] = x4.w;
    }
    __syncthreads();

    const int wv = __builtin_amdgcn_readfirstlane(tid >> 6);  // K-quarter [0,4)
    const int c  = tid & 63;
    const int cx = c > 60 ? 60 : c;         // dup lanes clamped

    const float* wq = sw + wv * 480;            // uniform -> broadcast reads
    const float* x0 = simg + (cx + wv) * CHS;   // chunk = c + wv; ONE base

    float acc[4][NCLS];
    #pragma unroll
    for (int t = 0; t < 4; ++t)
        #pragma unroll
        for (int k = 0; k < NCLS; ++k) acc[t][k] = 0.f;

    #pragma unroll
    for (int j = 0; j < 24; ++j) {          // K-pair within quarter
        const float4 A0 = *(const float4*)(wq + j * 20);      // broadcast b128
        const float4 A1 = *(const float4*)(wq + j * 20 + 4);
        const float4 A2 = *(const float4*)(wq + j * 20 + 8);
        const float4 A3 = *(const float4*)(wq + j * 20 + 12);
        const float4 A4 = *(const float4*)(wq + j * 20 + 16);
        const float w0[NCLS] = {A0.x,A0.y,A0.z,A0.w,A1.x,A1.y,A1.z,A1.w,A2.x,A2.y};
        const float w1[NCLS] = {A2.z,A2.w,A3.x,A3.y,A3.z,A3.w,A4.x,A4.y,A4.z,A4.w};
        #pragma unroll
        for (int t = 0; t < 4; ++t) {
            const float2 x = *(const float2*)(x0 + t * ROWF + 2 * j); // imm off
            #pragma unroll
            for (int k = 0; k < NCLS; ++k) {
                acc[t][k] = fmaf(x.x, w0[k], acc[t][k]);
                acc[t][k] = fmaf(x.y, w1[k], acc[t][k]);
            }
        }
    }

    // ---- cross-wave K-sum in LDS (reuse simg), store 610/output-row ----
    __syncthreads();                 // all img reads done
    float* scratch = simg;           // [wv][t][640]
    {
        float* sc = scratch + wv * 2560 + c * 10;
        #pragma unroll
        for (int t = 0; t < 4; ++t)
            #pragma unroll
            for (int k = 0; k < NCLS; ++k)
                sc[t * 640 + k] = acc[t][k];
    }
    __syncthreads();
    for (int u = tid; u < 2560; u += 256) {
        const int t = u / 640, e = u - t * 640;
        const int rr = 4 * rg + t;
        if (rr <= 60 && e < 610) {
            const int b = t * 640 + e;
            part[(size_t)(rr * 64 + wr) * PROW + e] =
                scratch[b] + scratch[2560 + b] + scratch[5120 + b] + scratch[7680 + b];
        }
    }
}

// ---------------------------------------------------------------------------
// Kernel 2: sum 64 wr-slices per output row + bias + softmax + prob + mask.
// One block per r.
// ---------------------------------------------------------------------------
__global__ __launch_bounds__(256) void wod_reduce(
    const float* __restrict__ part,   // (61*64, PROW)
    const float* __restrict__ bias,   // (10)
    float* __restrict__ out_prob,     // (61,61,10)
    int* __restrict__ mask)           // (10,3721)
{
    __shared__ float lg[610];
    const int r   = blockIdx.x;
    const int tid = threadIdx.x;
    const float* pb = part + (size_t)r * 64 * PROW;

    for (int t = tid; t < 610; t += 256) {
        float s = bias[t - (t / 10) * 10];
        #pragma unroll 8
        for (int wr = 0; wr < 64; ++wr) s += pb[wr * PROW + t];
        lg[t] = s;
    }
    __syncthreads();

    for (int c = tid; c < CG; c += 256) {
        float l[NCLS];
        #pragma unroll
        for (int k = 0; k < NCLS; ++k) l[k] = lg[c * 10 + k];
        float m = -1e30f;
        #pragma unroll
        for (int k = 0; k < NCLS; ++k) m = fmaxf(m, l[k]);
        float ex[NCLS], sm = 0.f;
        #pragma unroll
        for (int k = 0; k < NCLS; ++k) { ex[k] = expf(l[k] - m); sm += ex[k]; }
        const float inv = 1.f / sm;
        const int cell = r * CG + c;
        #pragma unroll
        for (int k = 0; k < NCLS; ++k) {
            const float pr = ex[k] * inv;
            out_prob[cell * 10 + k] = pr;
            mask[k * NP + cell] = (pr > THRESHV) ? 1 : 0;
        }
    }
}

// ---------------------------------------------------------------------------
// Kernel 3: connected components (min-label propagation in LDS) + labels +
// boxes + valid, all fused. One block per class. (Unchanged, proven.)
// ---------------------------------------------------------------------------
__global__ __launch_bounds__(256) void wod_cc(
    const int* __restrict__ mask,     // (10,3721)
    float* __restrict__ out_lbl,      // (61,61,10) as float
    float* __restrict__ out_box,      // (10,3722,4)
    float* __restrict__ out_valid)    // (10,3722)
{
    const int k = blockIdx.x;
    const int tid = threadIdx.x;
    __shared__ int lbl[NP];
    __shared__ int ext0[NSEG], ext1[NSEG];
    __shared__ int changed;

    const int* mk = mask + k * NP;
    for (int idx = tid; idx < NP; idx += 256)
        lbl[idx] = mk[idx] ? (idx + 1) : 0;
    if (tid == 0) changed = 0;
    __syncthreads();

    for (;;) {
        for (int idx = tid; idx < NP; idx += 256) {
            int v = lbl[idx];
            if (v) {
                const int rr = idx / CG;
                const int cc = idx - rr * CG;
                int best = v;
                if (rr > 0)      { int n = lbl[idx - CG]; if (n && n < best) best = n; }
                if (rr < RG - 1) { int n = lbl[idx + CG]; if (n && n < best) best = n; }
                if (cc > 0)      { int n = lbl[idx - 1];  if (n && n < best) best = n; }
                if (cc < CG - 1) { int n = lbl[idx + 1];  if (n && n < best) best = n; }
                if (best < v) { lbl[idx] = best; changed = 1; }
            }
        }
        __syncthreads();
        const bool stop = (changed == 0);
        __syncthreads();           // all reads of `changed` done before reset
        if (stop) break;
        if (tid == 0) changed = 0;
        __syncthreads();
    }

    // labels out (transposed to (r,c,k))
    for (int idx = tid; idx < NP; idx += 256)
        out_lbl[idx * NCLS + k] = (float)lbl[idx];

    float* boxk = out_box + k * NSEG * 4;
    float* valk = out_valid + k * NSEG;

    // pass 1: rmin / cmin
    for (int s2 = tid; s2 < NSEG; s2 += 256) { ext0[s2] = BIGI; ext1[s2] = BIGI; }
    __syncthreads();
    for (int idx = tid; idx < NP; idx += 256) {
        const int v = lbl[idx];
        if (v) {
            const int rr = idx / CG, cc = idx - rr * CG;
            atomicMin(&ext0[v], rr);
            atomicMin(&ext1[v], cc);
        }
    }
    __syncthreads();
    for (int s2 = tid; s2 < NSEG; s2 += 256) {
        const bool valid = (s2 > 0) && (ext0[s2] != BIGI);
        boxk[s2 * 4 + 0] = valid ? (float)(ext0[s2] - 1) : -1.f;
        boxk[s2 * 4 + 1] = valid ? (float)(ext1[s2] - 1) : -1.f;
        valk[s2] = valid ? 1.f : 0.f;
    }
    __syncthreads();

    // pass 2: rmax / cmax
    for (int s2 = tid; s2 < NSEG; s2 += 256) { ext0[s2] = -1; ext1[s2] = -1; }
    __syncthreads();
    for (int idx = tid; idx < NP; idx += 256) {
        const int v = lbl[idx];
        if (v) {
            const int rr = idx / CG, cc = idx - rr * CG;
            atomicMax(&ext0[v], rr);
            atomicMax(&ext1[v], cc);
        }
    }
    __syncthreads();
    for (int s2 = tid; s2 < NSEG; s2 += 256) {
        const bool valid = (s2 > 0) && (ext0[s2] >= 0);
        boxk[s2 * 4 + 2] = valid ? (float)(ext0[s2] + 1) : -1.f;
        boxk[s2 * 4 + 3] = valid ? (float)(ext1[s2] + 1) : -1.f;
    }
}

// ---------------------------------------------------------------------------
extern "C" void kernel_launch(void* const* d_in, const int* in_sizes, int n_in,
                              void* d_out, int out_size, void* d_ws, size_t ws_size,
                              hipStream_t stream) {
    (void)in_sizes; (void)n_in; (void)out_size; (void)ws_size;
    const float* img = (const float*)d_in[0];
    const float* W   = (const float*)d_in[1];
    const float* b   = (const float*)d_in[2];

    float* out       = (float*)d_out;
    float* out_prob  = out;                       // 37210
    float* out_lbl   = out + 37210;               // 37210
    float* out_box   = out + 74420;               // 148880
    float* out_valid = out + 223300;              // 37220

    int*   mask = (int*)d_ws;                        // 10*3721 ints
    float* part = (float*)((int*)d_ws + NCLS * NP);  // 61*64*640 floats ~10MB

    hipLaunchKernelGGL(wod_logits_part, dim3(NBLK), dim3(256), 0, stream,
                       img, W, part);
    hipLaunchKernelGGL(wod_reduce, dim3(RG), dim3(256), 0, stream,
                       part, b, out_prob, mask);
    hipLaunchKernelGGL(wod_cc, dim3(NCLS), dim3(256), 0, stream,
                       mask, out_lbl, out_box, out_valid);
}

// Round 16
// 54.935 us; speedup vs baseline: 1.7034x; 1.6714x over previous
//
#include <hip/hip_runtime.h>
#include <math.h>

#define RG 61
#define CG 61
#define NP 3721           // RG*CG
#define NSEG 3722         // NP+1
#define NCLS 10
#define THRESHV 0.7f
#define BIGI 0x3FFFFFFF

#define MT 3              // output rows per block
#define NRG 21            // ceil(61/3)
#define NBLK (64*NRG)     // 1344
#define CHS 49            // odd chunk stride -> ds_read2 2-way-free banking
#define ROWF (64*CHS)     // 3136 floats per staged row
#define PROW 640          // part row stride (610 used)

// readlane: uniformize one lane's float into an SGPR (imm lane)
__device__ __forceinline__ float rl(float v, int l) {
    return __builtin_bit_cast(float,
        __builtin_amdgcn_readlane(__builtin_bit_cast(int, v), l));
}
#define WCOMP(WB, W) (((W) & 3) == 0 ? (WB).x : ((W) & 3) == 1 ? (WB).y : \
                      ((W) & 3) == 2 ? (WB).z : (WB).w)
#define RLW(WB, W) rl(WCOMP(WB, (W)), (W) >> 2)

// one K-pair: 20 readlane (W -> SGPRs) + 3x ds_read2_b32 + 60 v_fmac
#define PAIR(WB, CH, P) { \
    float w_[20]; \
    _Pragma("unroll") \
    for (int k = 0; k < 20; ++k) w_[k] = RLW(WB, (P) * 20 + k); \
    _Pragma("unroll") \
    for (int t = 0; t < MT; ++t) { \
        const float xx = x0[t * ROWF + (CH) * 24 + 2 * (P)]; \
        const float xy = x0[t * ROWF + (CH) * 24 + 2 * (P) + 1]; \
        _Pragma("unroll") \
        for (int k = 0; k < NCLS; ++k) { \
            acc[t][k] = fmaf(xx, w_[k],      acc[t][k]); \
            acc[t][k] = fmaf(xy, w_[k + 10], acc[t][k]); \
        } } }

#define CHUNK(WB, CH) \
    PAIR(WB, CH, 0)  PAIR(WB, CH, 1)  PAIR(WB, CH, 2)  PAIR(WB, CH, 3)  \
    PAIR(WB, CH, 4)  PAIR(WB, CH, 5)  PAIR(WB, CH, 6)  PAIR(WB, CH, 7)  \
    PAIR(WB, CH, 8)  PAIR(WB, CH, 9)  PAIR(WB, CH, 10) PAIR(WB, CH, 11)

// ---------------------------------------------------------------------------
// Kernel 1: partial logits. Block = (wr, rg3): window row wr, output rows
// 3*rg3..+2. Wave wv = K-quarter (24 pairs); lane = column c.
// W path: each lane loads float4 of the wave's W half-chunk from GLOBAL
// (coalesced, 2 loads/wave total, latency amortized over ~7680cy FMA);
// per pair the 20 wave-uniform W floats are extracted via v_readlane (imm
// lane) into SGPRs -> v_fmac(v,s,v). ZERO W traffic on the DS pipe (R10's
// 60cy/pair broadcast cost eliminated). img: 3 rows chunked [ch][CHS=49],
// one merged ds_read2_b32 per (pair,row). LDS 37632B -> 4 blocks/CU.
// ---------------------------------------------------------------------------
__global__ __launch_bounds__(256, 4) void wod_logits_part(
    const float* __restrict__ img,   // (1024,1024,3)
    const float* __restrict__ W,     // (12288,10)
    float* __restrict__ part)        // (61*64, PROW)
{
    __shared__ float simg[MT * ROWF]; // 37632 B
    const int tid = threadIdx.x;
    // bijective XCD swizzle: 1344 = 8*168
    const int o   = (blockIdx.x & 7) * 168 + (blockIdx.x >> 3);
    const int wr  = o / NRG;          // window row [0,64)
    const int rg3 = o - wr * NRG;     // output-row triple [0,21)

    // ---- stage MT image rows (rr = 3*rg3+t clamped), chunked [ch][CHS] ----
    for (int u = tid; u < MT * 768; u += 256) {
        const int t  = u / 768;
        const int v  = u - t * 768;
        const int p0 = v * 4;
        int rr = MT * rg3 + t; if (rr > 60) rr = 60;
        const float4 x4 = *(const float4*)(img + (size_t)(16 * rr + wr) * 3072 + p0);
        const int ch = p0 / 48;              // p0%48 in {0,..,44}: never crosses
        float* d = simg + t * ROWF + ch * CHS + (p0 - ch * 48);
        d[0] = x4.x; d[1] = x4.y; d[2] = x4.z; d[3] = x4.w;
    }
    __syncthreads();

    const int wv = __builtin_amdgcn_readfirstlane(tid >> 6);  // K-quarter [0,4)
    const int c  = tid & 63;
    const int cx = c > 60 ? 60 : c;          // dup lanes clamped (discarded)

    // W: lane ll holds float4 = words [4ll,4ll+3] of the 240-float half-chunk
    const float* wsrc = W + wr * 1920 + wv * 480;
    const int ll = c < 60 ? c : 59;
    const float4 wA = *(const float4*)(wsrc + 4 * ll);        // chunk 0
    const float4 wB = *(const float4*)(wsrc + 240 + 4 * ll);  // chunk 1

    const float* x0 = simg + (cx + wv) * CHS;  // e48 = wv always (m=12ch+p<24)

    float acc[MT][NCLS];
    #pragma unroll
    for (int t = 0; t < MT; ++t)
        #pragma unroll
        for (int k = 0; k < NCLS; ++k) acc[t][k] = 0.f;

    CHUNK(wA, 0)
    CHUNK(wB, 1)

    // ---- cross-wave K-sum in LDS (reuse simg: need 4*MT*640=7680f < 9408) ----
    __syncthreads();                 // all img reads done
    float* scratch = simg;           // [wv][t][640]
    {
        float* sc = scratch + wv * (MT * 640) + c * 10;
        #pragma unroll
        for (int t = 0; t < MT; ++t)
            #pragma unroll
            for (int k = 0; k < NCLS; ++k)
                sc[t * 640 + k] = acc[t][k];
    }
    __syncthreads();
    for (int u = tid; u < MT * 640; u += 256) {
        const int t = u / 640, e = u - t * 640;
        const int rr = MT * rg3 + t;
        if (rr <= 60 && e < 610) {
            part[(size_t)(rr * 64 + wr) * PROW + e] =
                scratch[u] + scratch[MT * 640 + u] +
                scratch[2 * MT * 640 + u] + scratch[3 * MT * 640 + u];
        }
    }
}

// ---------------------------------------------------------------------------
// Kernel 2: sum 64 wr-slices per output row + bias + softmax + prob + mask.
// One block per r.
// ---------------------------------------------------------------------------
__global__ __launch_bounds__(256) void wod_reduce(
    const float* __restrict__ part,   // (61*64, PROW)
    const float* __restrict__ bias,   // (10)
    float* __restrict__ out_prob,     // (61,61,10)
    int* __restrict__ mask)           // (10,3721)
{
    __shared__ float lg[610];
    const int r   = blockIdx.x;
    const int tid = threadIdx.x;
    const float* pb = part + (size_t)r * 64 * PROW;

    for (int t = tid; t < 610; t += 256) {
        float s = bias[t - (t / 10) * 10];
        #pragma unroll 8
        for (int wr = 0; wr < 64; ++wr) s += pb[wr * PROW + t];
        lg[t] = s;
    }
    __syncthreads();

    for (int c = tid; c < CG; c += 256) {
        float l[NCLS];
        #pragma unroll
        for (int k = 0; k < NCLS; ++k) l[k] = lg[c * 10 + k];
        float m = -1e30f;
        #pragma unroll
        for (int k = 0; k < NCLS; ++k) m = fmaxf(m, l[k]);
        float ex[NCLS], sm = 0.f;
        #pragma unroll
        for (int k = 0; k < NCLS; ++k) { ex[k] = expf(l[k] - m); sm += ex[k]; }
        const float inv = 1.f / sm;
        const int cell = r * CG + c;
        #pragma unroll
        for (int k = 0; k < NCLS; ++k) {
            const float pr = ex[k] * inv;
            out_prob[cell * 10 + k] = pr;
            mask[k * NP + cell] = (pr > THRESHV) ? 1 : 0;
        }
    }
}

// ---------------------------------------------------------------------------
// Kernel 3: connected components (min-label propagation in LDS) + labels +
// boxes + valid, all fused. One block per class. (Unchanged, proven.)
// ---------------------------------------------------------------------------
__global__ __launch_bounds__(256) void wod_cc(
    const int* __restrict__ mask,     // (10,3721)
    float* __restrict__ out_lbl,      // (61,61,10) as float
    float* __restrict__ out_box,      // (10,3722,4)
    float* __restrict__ out_valid)    // (10,3722)
{
    const int k = blockIdx.x;
    const int tid = threadIdx.x;
    __shared__ int lbl[NP];
    __shared__ int ext0[NSEG], ext1[NSEG];
    __shared__ int changed;

    const int* mk = mask + k * NP;
    for (int idx = tid; idx < NP; idx += 256)
        lbl[idx] = mk[idx] ? (idx + 1) : 0;
    if (tid == 0) changed = 0;
    __syncthreads();

    for (;;) {
        for (int idx = tid; idx < NP; idx += 256) {
            int v = lbl[idx];
            if (v) {
                const int rr = idx / CG;
                const int cc = idx - rr * CG;
                int best = v;
                if (rr > 0)      { int n = lbl[idx - CG]; if (n && n < best) best = n; }
                if (rr < RG - 1) { int n = lbl[idx + CG]; if (n && n < best) best = n; }
                if (cc > 0)      { int n = lbl[idx - 1];  if (n && n < best) best = n; }
                if (cc < CG - 1) { int n = lbl[idx + 1];  if (n && n < best) best = n; }
                if (best < v) { lbl[idx] = best; changed = 1; }
            }
        }
        __syncthreads();
        const bool stop = (changed == 0);
        __syncthreads();           // all reads of `changed` done before reset
        if (stop) break;
        if (tid == 0) changed = 0;
        __syncthreads();
    }

    // labels out (transposed to (r,c,k))
    for (int idx = tid; idx < NP; idx += 256)
        out_lbl[idx * NCLS + k] = (float)lbl[idx];

    float* boxk = out_box + k * NSEG * 4;
    float* valk = out_valid + k * NSEG;

    // pass 1: rmin / cmin
    for (int s2 = tid; s2 < NSEG; s2 += 256) { ext0[s2] = BIGI; ext1[s2] = BIGI; }
    __syncthreads();
    for (int idx = tid; idx < NP; idx += 256) {
        const int v = lbl[idx];
        if (v) {
            const int rr = idx / CG, cc = idx - rr * CG;
            atomicMin(&ext0[v], rr);
            atomicMin(&ext1[v], cc);
        }
    }
    __syncthreads();
    for (int s2 = tid; s2 < NSEG; s2 += 256) {
        const bool valid = (s2 > 0) && (ext0[s2] != BIGI);
        boxk[s2 * 4 + 0] = valid ? (float)(ext0[s2] - 1) : -1.f;
        boxk[s2 * 4 + 1] = valid ? (float)(ext1[s2] - 1) : -1.f;
        valk[s2] = valid ? 1.f : 0.f;
    }
    __syncthreads();

    // pass 2: rmax / cmax
    for (int s2 = tid; s2 < NSEG; s2 += 256) { ext0[s2] = -1; ext1[s2] = -1; }
    __syncthreads();
    for (int idx = tid; idx < NP; idx += 256) {
        const int v = lbl[idx];
        if (v) {
            const int rr = idx / CG, cc = idx - rr * CG;
            atomicMax(&ext0[v], rr);
            atomicMax(&ext1[v], cc);
        }
    }
    __syncthreads();
    for (int s2 = tid; s2 < NSEG; s2 += 256) {
        const bool valid = (s2 > 0) && (ext0[s2] >= 0);
        boxk[s2 * 4 + 2] = valid ? (float)(ext0[s2] + 1) : -1.f;
        boxk[s2 * 4 + 3] = valid ? (float)(ext1[s2] + 1) : -1.f;
    }
}

// ---------------------------------------------------------------------------
extern "C" void kernel_launch(void* const* d_in, const int* in_sizes, int n_in,
                              void* d_out, int out_size, void* d_ws, size_t ws_size,
                              hipStream_t stream) {
    (void)in_sizes; (void)n_in; (void)out_size; (void)ws_size;
    const float* img = (const float*)d_in[0];
    const float* W   = (const float*)d_in[1];
    const float* b   = (const float*)d_in[2];

    float* out       = (float*)d_out;
    float* out_prob  = out;                       // 37210
    float* out_lbl   = out + 37210;               // 37210
    float* out_box   = out + 74420;               // 148880
    float* out_valid = out + 223300;              // 37220

    int*   mask = (int*)d_ws;                        // 10*3721 ints
    float* part = (float*)((int*)d_ws + NCLS * NP);  // 61*64*640 floats ~10MB

    hipLaunchKernelGGL(wod_logits_part, dim3(NBLK), dim3(256), 0, stream,
                       img, W, part);
    hipLaunchKernelGGL(wod_reduce, dim3(RG), dim3(256), 0, stream,
                       part, b, out_prob, mask);
    hipLaunchKernelGGL(wod_cc, dim3(NCLS), dim3(256), 0, stream,
                       mask, out_lbl, out_box, out_valid);
}

// Round 17
// 52.081 us; speedup vs baseline: 1.7967x; 1.0548x over previous
//
#include <hip/hip_runtime.h>
#include <math.h>

#define RG 61
#define CG 61
#define NP 3721           // RG*CG
#define NSEG 3722         // NP+1
#define NCLS 10
#define THRESHV 0.7f
#define BIGI 0x3FFFFFFF

#define MT 3              // output rows per block
#define NRG3 21           // ceil(61/3)
#define NBLK (64*NRG3)    // 1344
#define CHS 49            // odd chunk stride -> img reads 2-way-free banking
#define ROWF (64*CHS)     // 3136 floats per staged row
#define PROW 640          // part row stride (610 used)

// ---------------------------------------------------------------------------
// Kernel 1: partial logits — R10's PROVEN DS-broadcast scheme (its model
// matched measurement exactly), amortized (MT=3) and at high occupancy.
// Block = (wr, rg3): one window row, 3 output rows. 512 threads = 8 waves:
// wave (q,h) = K-quarter q, pair-half h (12 pairs). Lane = column c.
// Per pair: 5 ds_read_b128 W broadcast (60cy) + 3 ds_read2_b32 img (18cy)
// feeding 60 v_fmac (120cy). DS model: 1344*8*12*78 / 256 CU = 16.4us.
// LDS 45312B -> 3 blocks/CU = 24 waves/CU = 6/SIMD (R10 hid DS latency at
// 4/SIMD; R15's failure was 2/SIMD). launch_bounds(512,6) caps VGPR at 85.
// NO readlane (R16: SGPR hazards), NO SMEM (R14), NO global in loop (R2-6).
// ---------------------------------------------------------------------------
__global__ __launch_bounds__(512, 6) void wod_logits_part(
    const float* __restrict__ img,   // (1024,1024,3)
    const float* __restrict__ W,     // (12288,10)
    float* __restrict__ part)        // (61*64, PROW)
{
    __shared__ float simg[MT * ROWF]; // 37632 B
    __shared__ float sw[1920];        // 7680 B
    const int tid = threadIdx.x;
    // bijective XCD swizzle: 1344 = 8*168
    const int o   = (blockIdx.x & 7) * 168 + (blockIdx.x >> 3);
    const int wr  = o / NRG3;         // window row [0,64)
    const int rg3 = o - wr * NRG3;    // output-row triple [0,21)

    // ---- stage W row-slice: 1920 contiguous floats ----
    if (tid < 480)
        *(float4*)(sw + tid * 4) = *(const float4*)(W + wr * 1920 + tid * 4);

    // ---- stage MT image rows (rr = 3*rg3+t clamped), chunked [ch][CHS] ----
    for (int u = tid; u < MT * 768; u += 512) {
        const int t  = u / 768;
        const int v  = u - t * 768;
        const int p0 = v * 4;
        int rr = MT * rg3 + t; if (rr > 60) rr = 60;
        const float4 x4 = *(const float4*)(img + (size_t)(16 * rr + wr) * 3072 + p0);
        const int ch = p0 / 48;       // p0%48 in {0,..,44}: never crosses
        float* d = simg + t * ROWF + ch * CHS + (p0 - ch * 48);
        d[0] = x4.x; d[1] = x4.y; d[2] = x4.z; d[3] = x4.w;
    }
    __syncthreads();

    const int w8 = tid >> 6;          // wave [0,8)
    const int q  = w8 & 3;            // K-quarter
    const int h  = w8 >> 2;           // pair-half: pairs [12h, 12h+12)
    const int c  = tid & 63;
    const int cx = c > 60 ? 60 : c;   // dup lanes clamped (discarded later)

    const float* wq = sw + q * 480;              // uniform -> broadcast b128
    const float* x0 = simg + (cx + q) * CHS;     // chunk c+q <= 63

    float acc[MT][NCLS];
    #pragma unroll
    for (int t = 0; t < MT; ++t)
        #pragma unroll
        for (int k = 0; k < NCLS; ++k) acc[t][k] = 0.f;

    #pragma unroll
    for (int j = 0; j < 12; ++j) {
        const int p = 12 * h + j;                // pair [0,24): elems 2p,2p+1
        const float4 A0 = *(const float4*)(wq + 20 * p);
        const float4 A1 = *(const float4*)(wq + 20 * p + 4);
        const float4 A2 = *(const float4*)(wq + 20 * p + 8);
        const float4 A3 = *(const float4*)(wq + 20 * p + 12);
        const float4 A4 = *(const float4*)(wq + 20 * p + 16);
        const float w0[NCLS] = {A0.x,A0.y,A0.z,A0.w,A1.x,A1.y,A1.z,A1.w,A2.x,A2.y};
        const float w1[NCLS] = {A2.z,A2.w,A3.x,A3.y,A3.z,A3.w,A4.x,A4.y,A4.z,A4.w};
        #pragma unroll
        for (int t = 0; t < MT; ++t) {
            const float xx = x0[t * ROWF + 2 * p];
            const float xy = x0[t * ROWF + 2 * p + 1];
            #pragma unroll
            for (int k = 0; k < NCLS; ++k) {
                acc[t][k] = fmaf(xx, w0[k], acc[t][k]);
                acc[t][k] = fmaf(xy, w1[k], acc[t][k]);
            }
        }
    }

    // ---- reduce: h-merge then q-sum, in reused simg (needs 30720B) ----
    __syncthreads();                  // all compute reads of simg/sw done
    float* scratch = simg;            // [q][t][640]
    if (h == 0) {
        float* sc = scratch + q * (MT * 640) + c * 10;
        #pragma unroll
        for (int t = 0; t < MT; ++t)
            #pragma unroll
            for (int k = 0; k < NCLS; ++k) sc[t * 640 + k] = acc[t][k];
    }
    __syncthreads();
    if (h == 1) {
        float* sc = scratch + q * (MT * 640) + c * 10;
        #pragma unroll
        for (int t = 0; t < MT; ++t)
            #pragma unroll
            for (int k = 0; k < NCLS; ++k) sc[t * 640 + k] += acc[t][k];
    }
    __syncthreads();
    for (int u = tid; u < MT * 640; u += 512) {
        const int t = u / 640, e = u - t * 640;
        const int rr = MT * rg3 + t;
        if (rr <= 60 && e < 610) {
            part[(size_t)(rr * 64 + wr) * PROW + e] =
                scratch[u] + scratch[MT * 640 + u] +
                scratch[2 * MT * 640 + u] + scratch[3 * MT * 640 + u];
        }
    }
}

// ---------------------------------------------------------------------------
// Kernel 2: sum 64 wr-slices per output row + bias + softmax + prob + mask.
// One block per r. (Proven.)
// ---------------------------------------------------------------------------
__global__ __launch_bounds__(256) void wod_reduce(
    const float* __restrict__ part,   // (61*64, PROW)
    const float* __restrict__ bias,   // (10)
    float* __restrict__ out_prob,     // (61,61,10)
    int* __restrict__ mask)           // (10,3721)
{
    __shared__ float lg[610];
    const int r   = blockIdx.x;
    const int tid = threadIdx.x;
    const float* pb = part + (size_t)r * 64 * PROW;

    for (int t = tid; t < 610; t += 256) {
        float s = bias[t - (t / 10) * 10];
        #pragma unroll 8
        for (int wr = 0; wr < 64; ++wr) s += pb[wr * PROW + t];
        lg[t] = s;
    }
    __syncthreads();

    for (int c = tid; c < CG; c += 256) {
        float l[NCLS];
        #pragma unroll
        for (int k = 0; k < NCLS; ++k) l[k] = lg[c * 10 + k];
        float m = -1e30f;
        #pragma unroll
        for (int k = 0; k < NCLS; ++k) m = fmaxf(m, l[k]);
        float ex[NCLS], sm = 0.f;
        #pragma unroll
        for (int k = 0; k < NCLS; ++k) { ex[k] = expf(l[k] - m); sm += ex[k]; }
        const float inv = 1.f / sm;
        const int cell = r * CG + c;
        #pragma unroll
        for (int k = 0; k < NCLS; ++k) {
            const float pr = ex[k] * inv;
            out_prob[cell * 10 + k] = pr;
            mask[k * NP + cell] = (pr > THRESHV) ? 1 : 0;
        }
    }
}

// ---------------------------------------------------------------------------
// Kernel 3: connected components (min-label propagation in LDS) + labels +
// boxes + valid, all fused. One block per class. (Unchanged, proven.)
// ---------------------------------------------------------------------------
__global__ __launch_bounds__(256) void wod_cc(
    const int* __restrict__ mask,     // (10,3721)
    float* __restrict__ out_lbl,      // (61,61,10) as float
    float* __restrict__ out_box,      // (10,3722,4)
    float* __restrict__ out_valid)    // (10,3722)
{
    const int k = blockIdx.x;
    const int tid = threadIdx.x;
    __shared__ int lbl[NP];
    __shared__ int ext0[NSEG], ext1[NSEG];
    __shared__ int changed;

    const int* mk = mask + k * NP;
    for (int idx = tid; idx < NP; idx += 256)
        lbl[idx] = mk[idx] ? (idx + 1) : 0;
    if (tid == 0) changed = 0;
    __syncthreads();

    for (;;) {
        for (int idx = tid; idx < NP; idx += 256) {
            int v = lbl[idx];
            if (v) {
                const int rr = idx / CG;
                const int cc = idx - rr * CG;
                int best = v;
                if (rr > 0)      { int n = lbl[idx - CG]; if (n && n < best) best = n; }
                if (rr < RG - 1) { int n = lbl[idx + CG]; if (n && n < best) best = n; }
                if (cc > 0)      { int n = lbl[idx - 1];  if (n && n < best) best = n; }
                if (cc < CG - 1) { int n = lbl[idx + 1];  if (n && n < best) best = n; }
                if (best < v) { lbl[idx] = best; changed = 1; }
            }
        }
        __syncthreads();
        const bool stop = (changed == 0);
        __syncthreads();           // all reads of `changed` done before reset
        if (stop) break;
        if (tid == 0) changed = 0;
        __syncthreads();
    }

    // labels out (transposed to (r,c,k))
    for (int idx = tid; idx < NP; idx += 256)
        out_lbl[idx * NCLS + k] = (float)lbl[idx];

    float* boxk = out_box + k * NSEG * 4;
    float* valk = out_valid + k * NSEG;

    // pass 1: rmin / cmin
    for (int s2 = tid; s2 < NSEG; s2 += 256) { ext0[s2] = BIGI; ext1[s2] = BIGI; }
    __syncthreads();
    for (int idx = tid; idx < NP; idx += 256) {
        const int v = lbl[idx];
        if (v) {
            const int rr = idx / CG, cc = idx - rr * CG;
            atomicMin(&ext0[v], rr);
            atomicMin(&ext1[v], cc);
        }
    }
    __syncthreads();
    for (int s2 = tid; s2 < NSEG; s2 += 256) {
        const bool valid = (s2 > 0) && (ext0[s2] != BIGI);
        boxk[s2 * 4 + 0] = valid ? (float)(ext0[s2] - 1) : -1.f;
        boxk[s2 * 4 + 1] = valid ? (float)(ext1[s2] - 1) : -1.f;
        valk[s2] = valid ? 1.f : 0.f;
    }
    __syncthreads();

    // pass 2: rmax / cmax
    for (int s2 = tid; s2 < NSEG; s2 += 256) { ext0[s2] = -1; ext1[s2] = -1; }
    __syncthreads();
    for (int idx = tid; idx < NP; idx += 256) {
        const int v = lbl[idx];
        if (v) {
            const int rr = idx / CG, cc = idx - rr * CG;
            atomicMax(&ext0[v], rr);
            atomicMax(&ext1[v], cc);
        }
    }
    __syncthreads();
    for (int s2 = tid; s2 < NSEG; s2 += 256) {
        const bool valid = (s2 > 0) && (ext0[s2] >= 0);
        boxk[s2 * 4 + 2] = valid ? (float)(ext0[s2] + 1) : -1.f;
        boxk[s2 * 4 + 3] = valid ? (float)(ext1[s2] + 1) : -1.f;
    }
}

// ---------------------------------------------------------------------------
extern "C" void kernel_launch(void* const* d_in, const int* in_sizes, int n_in,
                              void* d_out, int out_size, void* d_ws, size_t ws_size,
                              hipStream_t stream) {
    (void)in_sizes; (void)n_in; (void)out_size; (void)ws_size;
    const float* img = (const float*)d_in[0];
    const float* W   = (const float*)d_in[1];
    const float* b   = (const float*)d_in[2];

    float* out       = (float*)d_out;
    float* out_prob  = out;                       // 37210
    float* out_lbl   = out + 37210;               // 37210
    float* out_box   = out + 74420;               // 148880
    float* out_valid = out + 223300;              // 37220

    int*   mask = (int*)d_ws;                        // 10*3721 ints
    float* part = (float*)((int*)d_ws + NCLS * NP);  // 61*64*640 floats ~10MB

    hipLaunchKernelGGL(wod_logits_part, dim3(NBLK), dim3(512), 0, stream,
                       img, W, part);
    hipLaunchKernelGGL(wod_reduce, dim3(RG), dim3(256), 0, stream,
                       part, b, out_prob, mask);
    hipLaunchKernelGGL(wod_cc, dim3(NCLS), dim3(256), 0, stream,
                       mask, out_lbl, out_box, out_valid);
}